// Round 1
// baseline (761.546 us; speedup 1.0000x reference)
//
#include <hip/hip_runtime.h>
#include <hip/hip_bf16.h>
#include <math.h>

#define HEADS   4
#define CDIM    64
#define HIDDEN  256
#define FIN     128
#define NGRAPH  256
#define NPB     16   // nodes per block in GEMM

// ---------------- GEMM: h = x @ W, plus per-node attention dots ----------------
__global__ __launch_bounds__(256) void k_gemm(
    const float* __restrict__ x, const float* __restrict__ W,
    const float* __restrict__ att_s, const float* __restrict__ att_d,
    float* __restrict__ h, float* __restrict__ a_src, float* __restrict__ a_dst,
    int nNodes)
{
  __shared__ float xs[NPB][FIN];
  const int t  = threadIdx.x;          // output column j = head*64 + c
  const int n0 = blockIdx.x * NPB;

  #pragma unroll
  for (int r = 0; r < NPB * FIN / 256; ++r) {   // 8 iters
    int idx = r * 256 + t;
    int row = idx >> 7, col = idx & (FIN - 1);
    int g = n0 + row;
    xs[row][col] = (g < nNodes) ? x[(size_t)g * FIN + col] : 0.f;
  }
  __syncthreads();

  float acc[NPB];
  #pragma unroll
  for (int i = 0; i < NPB; ++i) acc[i] = 0.f;

  for (int k = 0; k < FIN; k += 4) {
    float w0 = W[(k + 0) * HIDDEN + t];
    float w1 = W[(k + 1) * HIDDEN + t];
    float w2 = W[(k + 2) * HIDDEN + t];
    float w3 = W[(k + 3) * HIDDEN + t];
    #pragma unroll
    for (int i = 0; i < NPB; ++i) {
      float4 xv = *(const float4*)&xs[i][k];   // same-address broadcast, conflict-free
      acc[i] = fmaf(xv.w, w3, fmaf(xv.z, w2, fmaf(xv.y, w1, fmaf(xv.x, w0, acc[i]))));
    }
  }

  const float as_w = att_s[t];   // att_src flattened [4][64] == [256]
  const float ad_w = att_d[t];
  const int lane = t & 63, head = t >> 6;   // wave w == head w

  for (int i = 0; i < NPB; ++i) {
    int g = n0 + i;
    if (g >= nNodes) break;
    h[(size_t)g * HIDDEN + t] = acc[i];
    float vs = acc[i] * as_w, vd = acc[i] * ad_w;
    #pragma unroll
    for (int off2 = 32; off2; off2 >>= 1) {
      vs += __shfl_xor(vs, off2, 64);
      vd += __shfl_xor(vd, off2, 64);
    }
    if (lane == 0) { a_src[g * HEADS + head] = vs; a_dst[g * HEADS + head] = vd; }
  }
}

// ---------------- degree histogram (incl. self loops) ----------------
__global__ __launch_bounds__(256) void k_hist(const int* __restrict__ ei,
                                              int* __restrict__ count, int E, int N)
{
  int i = blockIdx.x * blockDim.x + threadIdx.x;
  int stride = gridDim.x * blockDim.x;
  for (int e = i; e < E; e += stride) atomicAdd(&count[ei[E + e]], 1);
  for (int n = i; n < N; n += stride) atomicAdd(&count[n], 1);   // self loop
}

// ---------------- 3-kernel exclusive scan over counts ----------------
__global__ __launch_bounds__(256) void k_scan1(const int* __restrict__ cnt,
                                               int* __restrict__ offs,
                                               int* __restrict__ bsum, int n)
{
  int t = threadIdx.x, b = blockIdx.x;
  int i = b * 256 + t;
  int v = (i < n) ? cnt[i] : 0;
  int sc = v;
  #pragma unroll
  for (int d2 = 1; d2 < 64; d2 <<= 1) {
    int u = __shfl_up(sc, d2, 64);
    if ((t & 63) >= d2) sc += u;
  }
  __shared__ int wsum[4];
  if ((t & 63) == 63) wsum[t >> 6] = sc;
  __syncthreads();
  int base = 0;
  for (int w = 0; w < (t >> 6); ++w) base += wsum[w];
  int incl = sc + base;
  if (i < n) offs[i] = incl - v;          // exclusive within block
  if (t == 255) bsum[b] = incl;           // block total
}

__global__ __launch_bounds__(256) void k_scan2(const int* __restrict__ bsum,
                                               int* __restrict__ bsumo, int nb)
{
  int t = threadIdx.x;
  int v = (t < nb) ? bsum[t] : 0;
  int sc = v;
  #pragma unroll
  for (int d2 = 1; d2 < 64; d2 <<= 1) {
    int u = __shfl_up(sc, d2, 64);
    if ((t & 63) >= d2) sc += u;
  }
  __shared__ int wsum[4];
  if ((t & 63) == 63) wsum[t >> 6] = sc;
  __syncthreads();
  int base = 0;
  for (int w = 0; w < (t >> 6); ++w) base += wsum[w];
  int incl = sc + base;
  if (t < nb) bsumo[t] = incl - v;        // exclusive block offsets
}

__global__ __launch_bounds__(256) void k_scan3(int* __restrict__ offs,
                                               const int* __restrict__ bsumo,
                                               int* __restrict__ cursor, int n, int total)
{
  int t = threadIdx.x, b = blockIdx.x;
  int i = b * 256 + t;
  if (i < n) {
    int o = offs[i] + bsumo[b];
    offs[i] = o;
    cursor[i] = o;
  }
  if (i == 0) offs[n] = total;
}

// ---------------- edge pass: ee = exp(lrelu(a_src[s]+a_dst[d])), denom, CSR scatter ----------------
__global__ __launch_bounds__(256) void k_edge(
    const int* __restrict__ ei, const float* __restrict__ a_src, const float* __restrict__ a_dst,
    float* __restrict__ sden, int* __restrict__ cursor,
    int* __restrict__ ssrc, float4* __restrict__ see, int E, int N)
{
  int e = blockIdx.x * 256 + threadIdx.x;
  int tot = E + N;
  if (e >= tot) return;
  int s, d;
  if (e < E) { s = ei[e]; d = ei[E + e]; }
  else       { s = e - E; d = s; }        // self loop
  float4 ea = *(const float4*)&a_src[s * 4];
  float4 eb = *(const float4*)&a_dst[d * 4];
  float4 ee; float v;
  v = ea.x + eb.x; v = v > 0.f ? v : 0.2f * v; ee.x = expf(v);
  v = ea.y + eb.y; v = v > 0.f ? v : 0.2f * v; ee.y = expf(v);
  v = ea.z + eb.z; v = v > 0.f ? v : 0.2f * v; ee.z = expf(v);
  v = ea.w + eb.w; v = v > 0.f ? v : 0.2f * v; ee.w = expf(v);
  atomicAdd(&sden[d * 4 + 0], ee.x);
  atomicAdd(&sden[d * 4 + 1], ee.y);
  atomicAdd(&sden[d * 4 + 2], ee.z);
  atomicAdd(&sden[d * 4 + 3], ee.w);
  int pos = atomicAdd(&cursor[d], 1);
  ssrc[pos] = s;
  see[pos] = ee;
}

// ---------------- aggregation: one block per dst node; fused bias+ELU+pool ----------------
__global__ __launch_bounds__(256) void k_agg(
    const float* __restrict__ h, const int* __restrict__ offs, const int* __restrict__ ssrc,
    const float* __restrict__ see, const float* __restrict__ sden,
    const float* __restrict__ bias, const int* __restrict__ batch,
    float* __restrict__ pooled, float* __restrict__ cntg, int N)
{
  int n = blockIdx.x;
  int t = threadIdx.x;
  int head = t >> 6;
  int beg = offs[n], end = offs[n + 1];
  float invh = 1.0f / sden[n * 4 + head];
  float acc = 0.f;
  for (int k = beg; k < end; ++k) {
    int s = ssrc[k];                         // uniform scalar load
    float al = see[(size_t)k * 4 + head] * invh;
    acc = fmaf(h[(size_t)s * HIDDEN + t], al, acc);   // coalesced 1KB gather
  }
  float v2 = acc + bias[t];
  float o = v2 > 0.f ? v2 : expm1f(v2);      // ELU
  int g = batch[n];
  atomicAdd(&pooled[g * HIDDEN + t], o);
  if (t == 0) atomicAdd(&cntg[g], 1.0f);
}

// ---------------- final: mean pool + FC ----------------
__global__ __launch_bounds__(64) void k_fc(
    const float* __restrict__ pooled, const float* __restrict__ cntg,
    const float* __restrict__ fc_w, const float* __restrict__ fc_b, float* __restrict__ out)
{
  int g = blockIdx.x, l = threadIdx.x;
  float acc = 0.f;
  for (int j = l; j < HIDDEN; j += 64) acc += pooled[g * HIDDEN + j] * fc_w[j];
  #pragma unroll
  for (int off2 = 32; off2; off2 >>= 1) acc += __shfl_xor(acc, off2, 64);
  if (l == 0) out[g] = acc / fmaxf(cntg[g], 1.0f) + fc_b[0];
}

extern "C" void kernel_launch(void* const* d_in, const int* in_sizes, int n_in,
                              void* d_out, int out_size, void* d_ws, size_t ws_size,
                              hipStream_t stream)
{
  const float* x     = (const float*)d_in[0];
  const int*   ei    = (const int*)  d_in[1];   // [2,E] flat: [0..E)=src, [E..2E)=dst
  /* d_in[2] edge_attr: unused by reference */
  const int*   batch = (const int*)  d_in[3];
  const float* W     = (const float*)d_in[4];
  const float* att_s = (const float*)d_in[5];
  const float* att_d = (const float*)d_in[6];
  const float* bias  = (const float*)d_in[7];
  const float* fc_w  = (const float*)d_in[8];
  const float* fc_b  = (const float*)d_in[9];
  float* out = (float*)d_out;

  const int N   = in_sizes[0] / FIN;
  const int E   = in_sizes[1] / 2;
  const int TOT = E + N;

  char* p = (char*)d_ws;
  size_t o = 0;
  auto alloc = [&](size_t bytes) -> void* {
    void* r = p + o;
    o = (o + bytes + 255) & ~(size_t)255;
    return r;
  };
  // zero-init region first: one memset covers [sden | count | pooled | cntg]
  float* sden   = (float*)alloc((size_t)N * 4 * sizeof(float));
  int*   count  = (int*)  alloc((size_t)N * sizeof(int));
  float* pooled = (float*)alloc((size_t)NGRAPH * HIDDEN * sizeof(float));
  float* cntg   = (float*)alloc((size_t)NGRAPH * sizeof(float));
  size_t zeroBytes = o;
  float* h      = (float*)alloc((size_t)N * HIDDEN * sizeof(float));
  float* a_src  = (float*)alloc((size_t)N * 4 * sizeof(float));
  float* a_dst  = (float*)alloc((size_t)N * 4 * sizeof(float));
  int*   offs   = (int*)  alloc((size_t)(N + 1) * sizeof(int));
  int*   cursor = (int*)  alloc((size_t)N * sizeof(int));
  int*   bsum   = (int*)  alloc(1024);
  int*   bsumo  = (int*)  alloc(1024);
  int*   ssrc   = (int*)  alloc((size_t)TOT * sizeof(int));
  float* see    = (float*)alloc((size_t)TOT * 4 * sizeof(float));
  (void)ws_size; (void)n_in; (void)out_size;

  hipMemsetAsync(d_ws, 0, zeroBytes, stream);

  int gemmBlocks = (N + NPB - 1) / NPB;
  hipLaunchKernelGGL(k_gemm, dim3(gemmBlocks), dim3(256), 0, stream,
                     x, W, att_s, att_d, h, a_src, a_dst, N);
  hipLaunchKernelGGL(k_hist, dim3(2048), dim3(256), 0, stream, ei, count, E, N);
  int sb = (N + 255) / 256;
  hipLaunchKernelGGL(k_scan1, dim3(sb), dim3(256), 0, stream, count, offs, bsum, N);
  hipLaunchKernelGGL(k_scan2, dim3(1), dim3(256), 0, stream, bsum, bsumo, sb);
  hipLaunchKernelGGL(k_scan3, dim3(sb), dim3(256), 0, stream, offs, bsumo, cursor, N, TOT);
  hipLaunchKernelGGL(k_edge, dim3((TOT + 255) / 256), dim3(256), 0, stream,
                     ei, a_src, a_dst, sden, cursor, ssrc, (float4*)see, E, N);
  hipLaunchKernelGGL(k_agg, dim3(N), dim3(256), 0, stream,
                     h, offs, ssrc, see, sden, bias, batch, pooled, cntg, N);
  hipLaunchKernelGGL(k_fc, dim3(NGRAPH), dim3(64), 0, stream,
                     pooled, cntg, fc_w, fc_b, out);
}

// Round 2
// 451.189 us; speedup vs baseline: 1.6879x; 1.6879x over previous
//
#include <hip/hip_runtime.h>
#include <hip/hip_bf16.h>
#include <math.h>

#define HEADS   4
#define HIDDEN  256
#define FIN     128
#define NGRAPH  256
#define NPB     16   // nodes per block in GEMM
#define WPB     4    // waves (=nodes) per block in k_agg

// ---------------- GEMM: h = x @ W, plus per-node attention dots ----------------
__global__ __launch_bounds__(256) void k_gemm(
    const float* __restrict__ x, const float* __restrict__ W,
    const float* __restrict__ att_s, const float* __restrict__ att_d,
    float* __restrict__ h, float* __restrict__ a_src, float* __restrict__ a_dst,
    int nNodes)
{
  __shared__ float xs[NPB][FIN];
  const int t  = threadIdx.x;          // output column j = head*64 + c
  const int n0 = blockIdx.x * NPB;

  #pragma unroll
  for (int r = 0; r < NPB * FIN / 256; ++r) {   // 8 iters
    int idx = r * 256 + t;
    int row = idx >> 7, col = idx & (FIN - 1);
    int g = n0 + row;
    xs[row][col] = (g < nNodes) ? x[(size_t)g * FIN + col] : 0.f;
  }
  __syncthreads();

  float acc[NPB];
  #pragma unroll
  for (int i = 0; i < NPB; ++i) acc[i] = 0.f;

  for (int k = 0; k < FIN; k += 4) {
    float w0 = W[(k + 0) * HIDDEN + t];
    float w1 = W[(k + 1) * HIDDEN + t];
    float w2 = W[(k + 2) * HIDDEN + t];
    float w3 = W[(k + 3) * HIDDEN + t];
    #pragma unroll
    for (int i = 0; i < NPB; ++i) {
      float4 xv = *(const float4*)&xs[i][k];   // same-address broadcast, conflict-free
      acc[i] = fmaf(xv.w, w3, fmaf(xv.z, w2, fmaf(xv.y, w1, fmaf(xv.x, w0, acc[i]))));
    }
  }

  const float as_w = att_s[t];   // att_src flattened [4][64] == [256]
  const float ad_w = att_d[t];
  const int lane = t & 63, head = t >> 6;   // wave w == head w

  for (int i = 0; i < NPB; ++i) {
    int g = n0 + i;
    if (g >= nNodes) break;
    h[(size_t)g * HIDDEN + t] = acc[i];
    float vs = acc[i] * as_w, vd = acc[i] * ad_w;
    #pragma unroll
    for (int off2 = 32; off2; off2 >>= 1) {
      vs += __shfl_xor(vs, off2, 64);
      vd += __shfl_xor(vd, off2, 64);
    }
    if (lane == 0) { a_src[g * HEADS + head] = vs; a_dst[g * HEADS + head] = vd; }
  }
}

// ---------------- degree histogram (incl. self loops) ----------------
__global__ __launch_bounds__(256) void k_hist(const int* __restrict__ ei,
                                              int* __restrict__ count, int E, int N)
{
  int i = blockIdx.x * blockDim.x + threadIdx.x;
  int stride = gridDim.x * blockDim.x;
  for (int e = i; e < E; e += stride) atomicAdd(&count[ei[E + e]], 1);
  for (int n = i; n < N; n += stride) atomicAdd(&count[n], 1);   // self loop
}

// ---------------- 3-kernel exclusive scan over counts ----------------
__global__ __launch_bounds__(256) void k_scan1(const int* __restrict__ cnt,
                                               int* __restrict__ offs,
                                               int* __restrict__ bsum, int n)
{
  int t = threadIdx.x, b = blockIdx.x;
  int i = b * 256 + t;
  int v = (i < n) ? cnt[i] : 0;
  int sc = v;
  #pragma unroll
  for (int d2 = 1; d2 < 64; d2 <<= 1) {
    int u = __shfl_up(sc, d2, 64);
    if ((t & 63) >= d2) sc += u;
  }
  __shared__ int wsum[4];
  if ((t & 63) == 63) wsum[t >> 6] = sc;
  __syncthreads();
  int base = 0;
  for (int w = 0; w < (t >> 6); ++w) base += wsum[w];
  int incl = sc + base;
  if (i < n) offs[i] = incl - v;          // exclusive within block
  if (t == 255) bsum[b] = incl;           // block total
}

__global__ __launch_bounds__(256) void k_scan2(const int* __restrict__ bsum,
                                               int* __restrict__ bsumo, int nb)
{
  int t = threadIdx.x;
  int v = (t < nb) ? bsum[t] : 0;
  int sc = v;
  #pragma unroll
  for (int d2 = 1; d2 < 64; d2 <<= 1) {
    int u = __shfl_up(sc, d2, 64);
    if ((t & 63) >= d2) sc += u;
  }
  __shared__ int wsum[4];
  if ((t & 63) == 63) wsum[t >> 6] = sc;
  __syncthreads();
  int base = 0;
  for (int w = 0; w < (t >> 6); ++w) base += wsum[w];
  int incl = sc + base;
  if (t < nb) bsumo[t] = incl - v;        // exclusive block offsets
}

__global__ __launch_bounds__(256) void k_scan3(int* __restrict__ offs,
                                               const int* __restrict__ bsumo,
                                               int* __restrict__ cursor, int n, int total)
{
  int t = threadIdx.x, b = blockIdx.x;
  int i = b * 256 + t;
  if (i < n) {
    int o = offs[i] + bsumo[b];
    offs[i] = o;
    cursor[i] = o;
  }
  if (i == 0) offs[n] = total;
}

// ---------------- CSR scatter: only src indices; ee computed later in k_agg ----------------
__global__ __launch_bounds__(256) void k_scatter(
    const int* __restrict__ ei, int* __restrict__ cursor,
    int* __restrict__ ssrc, int E, int N)
{
  int e = blockIdx.x * 256 + threadIdx.x;
  int tot = E + N;
  if (e >= tot) return;
  int s, d;
  if (e < E) { s = ei[e]; d = ei[E + e]; }
  else       { s = e - E; d = s; }        // self loop
  int pos = atomicAdd(&cursor[d], 1);
  ssrc[pos] = s;
}

// ---------------- aggregation: one WAVE per node; fused softmax+bias+ELU ----------------
// lane covers columns [4*lane, 4*lane+4); head = lane>>4.
__global__ __launch_bounds__(256) void k_agg(
    const float* __restrict__ h, const int* __restrict__ offs, const int* __restrict__ ssrc,
    const float* __restrict__ a_src, const float* __restrict__ a_dst,
    const float* __restrict__ bias, const int* __restrict__ batch,
    float* __restrict__ outn, float* __restrict__ pooled, float* __restrict__ cntg,
    int N, int useAtomic)
{
  const int wid = blockIdx.x * WPB + (threadIdx.x >> 6);
  if (wid >= N) return;
  const int lane = threadIdx.x & 63;
  const int head = lane >> 4;
  const int col  = lane << 2;

  const int beg = offs[wid], end = offs[wid + 1];
  const float ad = a_dst[wid * 4 + head];

  float4 acc = make_float4(0.f, 0.f, 0.f, 0.f);
  float den = 0.f;
  int k = beg;
  for (; k + 4 <= end; k += 4) {
    // all-uniform: compiler emits s_load_dwordx4
    int s0 = ssrc[k + 0], s1 = ssrc[k + 1], s2 = ssrc[k + 2], s3 = ssrc[k + 3];
    // issue the 8 independent gathers before any consumption (MLP)
    float e0 = a_src[s0 * 4 + head];
    float e1 = a_src[s1 * 4 + head];
    float e2 = a_src[s2 * 4 + head];
    float e3 = a_src[s3 * 4 + head];
    float4 h0 = *(const float4*)&h[(size_t)s0 * HIDDEN + col];
    float4 h1 = *(const float4*)&h[(size_t)s1 * HIDDEN + col];
    float4 h2 = *(const float4*)&h[(size_t)s2 * HIDDEN + col];
    float4 h3 = *(const float4*)&h[(size_t)s3 * HIDDEN + col];
    e0 += ad; e1 += ad; e2 += ad; e3 += ad;
    e0 = e0 > 0.f ? e0 : 0.2f * e0;
    e1 = e1 > 0.f ? e1 : 0.2f * e1;
    e2 = e2 > 0.f ? e2 : 0.2f * e2;
    e3 = e3 > 0.f ? e3 : 0.2f * e3;
    float w0 = __expf(e0), w1 = __expf(e1), w2 = __expf(e2), w3 = __expf(e3);
    den += (w0 + w1) + (w2 + w3);
    acc.x = fmaf(h0.x, w0, acc.x); acc.y = fmaf(h0.y, w0, acc.y);
    acc.z = fmaf(h0.z, w0, acc.z); acc.w = fmaf(h0.w, w0, acc.w);
    acc.x = fmaf(h1.x, w1, acc.x); acc.y = fmaf(h1.y, w1, acc.y);
    acc.z = fmaf(h1.z, w1, acc.z); acc.w = fmaf(h1.w, w1, acc.w);
    acc.x = fmaf(h2.x, w2, acc.x); acc.y = fmaf(h2.y, w2, acc.y);
    acc.z = fmaf(h2.z, w2, acc.z); acc.w = fmaf(h2.w, w2, acc.w);
    acc.x = fmaf(h3.x, w3, acc.x); acc.y = fmaf(h3.y, w3, acc.y);
    acc.z = fmaf(h3.z, w3, acc.z); acc.w = fmaf(h3.w, w3, acc.w);
  }
  for (; k < end; ++k) {
    int s = ssrc[k];
    float e = a_src[s * 4 + head] + ad;
    e = e > 0.f ? e : 0.2f * e;
    float w = __expf(e);
    float4 hv = *(const float4*)&h[(size_t)s * HIDDEN + col];
    den += w;
    acc.x = fmaf(hv.x, w, acc.x); acc.y = fmaf(hv.y, w, acc.y);
    acc.z = fmaf(hv.z, w, acc.z); acc.w = fmaf(hv.w, w, acc.w);
  }

  const float inv = 1.f / den;          // den > 0 guaranteed by self loop
  float4 bv = *(const float4*)&bias[col];
  float4 o;
  o.x = fmaf(acc.x, inv, bv.x); o.x = o.x > 0.f ? o.x : expm1f(o.x);
  o.y = fmaf(acc.y, inv, bv.y); o.y = o.y > 0.f ? o.y : expm1f(o.y);
  o.z = fmaf(acc.z, inv, bv.z); o.z = o.z > 0.f ? o.z : expm1f(o.z);
  o.w = fmaf(acc.w, inv, bv.w); o.w = o.w > 0.f ? o.w : expm1f(o.w);

  if (useAtomic) {
    int g = batch[wid];
    atomicAdd(&pooled[g * HIDDEN + col + 0], o.x);
    atomicAdd(&pooled[g * HIDDEN + col + 1], o.y);
    atomicAdd(&pooled[g * HIDDEN + col + 2], o.z);
    atomicAdd(&pooled[g * HIDDEN + col + 3], o.w);
    if (lane == 0) atomicAdd(&cntg[g], 1.0f);
  } else {
    *(float4*)&outn[(size_t)wid * HIDDEN + col] = o;
  }
}

// ---------------- per-graph mean pool + fused FC (no atomics) ----------------
__global__ __launch_bounds__(256) void k_pool(
    const float* __restrict__ outn, const int* __restrict__ batch,
    const float* __restrict__ fc_w, const float* __restrict__ fc_b,
    float* __restrict__ out, int N)
{
  const int g = blockIdx.x, t = threadIdx.x;
  // binary search: node range [lo,hi) of graph g (batch is sorted)
  int a = 0, b = N;
  while (a < b) { int m = (a + b) >> 1; if (batch[m] < g) a = m + 1; else b = m; }
  const int lo = a;
  b = N;
  while (a < b) { int m = (a + b) >> 1; if (batch[m] < g + 1) a = m + 1; else b = m; }
  const int hi = a;

  float acc = 0.f, acc2 = 0.f;
  int n = lo;
  for (; n + 2 <= hi; n += 2) {
    acc  += outn[(size_t)n * HIDDEN + t];
    acc2 += outn[(size_t)(n + 1) * HIDDEN + t];
  }
  if (n < hi) acc += outn[(size_t)n * HIDDEN + t];
  acc += acc2;

  float cnt = (float)(hi - lo);
  float pooledv = acc / fmaxf(cnt, 1.0f);
  float v = pooledv * fc_w[t];
  #pragma unroll
  for (int off2 = 32; off2; off2 >>= 1) v += __shfl_xor(v, off2, 64);
  __shared__ float ws4[4];
  if ((t & 63) == 0) ws4[t >> 6] = v;
  __syncthreads();
  if (t == 0) out[g] = ws4[0] + ws4[1] + ws4[2] + ws4[3] + fc_b[0];
}

// ---------------- fallback final: mean pool + FC from atomic-pooled ----------------
__global__ __launch_bounds__(64) void k_fc(
    const float* __restrict__ pooled, const float* __restrict__ cntg,
    const float* __restrict__ fc_w, const float* __restrict__ fc_b, float* __restrict__ out)
{
  int g = blockIdx.x, l = threadIdx.x;
  float acc = 0.f;
  for (int j = l; j < HIDDEN; j += 64) acc += pooled[g * HIDDEN + j] * fc_w[j];
  #pragma unroll
  for (int off2 = 32; off2; off2 >>= 1) acc += __shfl_xor(acc, off2, 64);
  if (l == 0) out[g] = acc / fmaxf(cntg[g], 1.0f) + fc_b[0];
}

extern "C" void kernel_launch(void* const* d_in, const int* in_sizes, int n_in,
                              void* d_out, int out_size, void* d_ws, size_t ws_size,
                              hipStream_t stream)
{
  const float* x     = (const float*)d_in[0];
  const int*   ei    = (const int*)  d_in[1];   // [2,E] flat: [0..E)=src, [E..2E)=dst
  /* d_in[2] edge_attr: unused by reference */
  const int*   batch = (const int*)  d_in[3];
  const float* W     = (const float*)d_in[4];
  const float* att_s = (const float*)d_in[5];
  const float* att_d = (const float*)d_in[6];
  const float* bias  = (const float*)d_in[7];
  const float* fc_w  = (const float*)d_in[8];
  const float* fc_b  = (const float*)d_in[9];
  float* out = (float*)d_out;

  const int N   = in_sizes[0] / FIN;
  const int E   = in_sizes[1] / 2;
  const int TOT = E + N;

  char* p = (char*)d_ws;
  size_t o = 0;
  auto alloc = [&](size_t bytes) -> void* {
    void* r = p + o;
    o = (o + bytes + 255) & ~(size_t)255;
    return r;
  };
  // zero-init region first: one memset covers [count | pooled | cntg]
  int*   count  = (int*)  alloc((size_t)N * sizeof(int));
  float* pooled = (float*)alloc((size_t)NGRAPH * HIDDEN * sizeof(float));
  float* cntg   = (float*)alloc((size_t)NGRAPH * sizeof(float));
  size_t zeroBytes = o;
  float* h      = (float*)alloc((size_t)N * HIDDEN * sizeof(float));
  float* a_src  = (float*)alloc((size_t)N * 4 * sizeof(float));
  float* a_dst  = (float*)alloc((size_t)N * 4 * sizeof(float));
  int*   offs   = (int*)  alloc((size_t)(N + 1) * sizeof(int));
  int*   cursor = (int*)  alloc((size_t)N * sizeof(int));
  int*   bsum   = (int*)  alloc(1024);
  int*   bsumo  = (int*)  alloc(1024);
  int*   ssrc   = (int*)  alloc((size_t)TOT * sizeof(int));
  size_t baseBytes = o;
  float* outn   = (float*)alloc((size_t)N * HIDDEN * sizeof(float));
  const int useAtomic = (o > ws_size) ? 1 : 0;   // fall back if ws too small
  (void)baseBytes; (void)n_in; (void)out_size;

  hipMemsetAsync(d_ws, 0, zeroBytes, stream);

  int gemmBlocks = (N + NPB - 1) / NPB;
  hipLaunchKernelGGL(k_gemm, dim3(gemmBlocks), dim3(256), 0, stream,
                     x, W, att_s, att_d, h, a_src, a_dst, N);
  hipLaunchKernelGGL(k_hist, dim3(2048), dim3(256), 0, stream, ei, count, E, N);
  int sb = (N + 255) / 256;
  hipLaunchKernelGGL(k_scan1, dim3(sb), dim3(256), 0, stream, count, offs, bsum, N);
  hipLaunchKernelGGL(k_scan2, dim3(1), dim3(256), 0, stream, bsum, bsumo, sb);
  hipLaunchKernelGGL(k_scan3, dim3(sb), dim3(256), 0, stream, offs, bsumo, cursor, N, TOT);
  hipLaunchKernelGGL(k_scatter, dim3((TOT + 255) / 256), dim3(256), 0, stream,
                     ei, cursor, ssrc, E, N);
  hipLaunchKernelGGL(k_agg, dim3((N + WPB - 1) / WPB), dim3(256), 0, stream,
                     h, offs, ssrc, a_src, a_dst, bias, batch,
                     outn, pooled, cntg, N, useAtomic);
  if (useAtomic) {
    hipLaunchKernelGGL(k_fc, dim3(NGRAPH), dim3(64), 0, stream,
                       pooled, cntg, fc_w, fc_b, out);
  } else {
    hipLaunchKernelGGL(k_pool, dim3(NGRAPH), dim3(256), 0, stream,
                       outn, batch, fc_w, fc_b, out, N);
  }
}

// Round 4
// 383.999 us; speedup vs baseline: 1.9832x; 1.1750x over previous
//
#include <hip/hip_runtime.h>
#include <hip/hip_bf16.h>
#include <math.h>

#define HEADS   4
#define HIDDEN  256
#define FIN     128
#define NGRAPH  256
#define NPB     16   // nodes per block in GEMM
#define WPB     4    // waves (=nodes) per block in k_agg

__device__ __forceinline__ float bf2f(unsigned short u) {
  union { unsigned int i; float f; } v; v.i = ((unsigned int)u) << 16; return v.f;
}
__device__ __forceinline__ unsigned short f2bf(float f) {
  union { float f; unsigned int i; } v; v.f = f;
  unsigned int b = v.i;
  b += 0x7FFFu + ((b >> 16) & 1u);   // round-to-nearest-even
  return (unsigned short)(b >> 16);
}

// ---------------- GEMM: h = x @ W (fp32 accum, bf16 store), + attention dots ----------------
__global__ __launch_bounds__(256) void k_gemm(
    const float* __restrict__ x, const float* __restrict__ W,
    const float* __restrict__ att_s, const float* __restrict__ att_d,
    unsigned short* __restrict__ h16, float* __restrict__ a_src, float* __restrict__ a_dst,
    int nNodes)
{
  __shared__ float xs[NPB][FIN];
  const int t  = threadIdx.x;          // output column j = head*64 + c
  const int n0 = blockIdx.x * NPB;

  #pragma unroll
  for (int r = 0; r < NPB * FIN / 256; ++r) {   // 8 iters
    int idx = r * 256 + t;
    int row = idx >> 7, col = idx & (FIN - 1);
    int g = n0 + row;
    xs[row][col] = (g < nNodes) ? x[(size_t)g * FIN + col] : 0.f;
  }
  __syncthreads();

  float acc[NPB];
  #pragma unroll
  for (int i = 0; i < NPB; ++i) acc[i] = 0.f;

  for (int k = 0; k < FIN; k += 4) {
    float w0 = W[(k + 0) * HIDDEN + t];
    float w1 = W[(k + 1) * HIDDEN + t];
    float w2 = W[(k + 2) * HIDDEN + t];
    float w3 = W[(k + 3) * HIDDEN + t];
    #pragma unroll
    for (int i = 0; i < NPB; ++i) {
      float4 xv = *(const float4*)&xs[i][k];   // same-address broadcast, conflict-free
      acc[i] = fmaf(xv.w, w3, fmaf(xv.z, w2, fmaf(xv.y, w1, fmaf(xv.x, w0, acc[i]))));
    }
  }

  const float as_w = att_s[t];   // att_src flattened [4][64] == [256]
  const float ad_w = att_d[t];
  const int lane = t & 63, head = t >> 6;   // wave w == head w

  for (int i = 0; i < NPB; ++i) {
    int g = n0 + i;
    if (g >= nNodes) break;
    h16[(size_t)g * HIDDEN + t] = f2bf(acc[i]);
    float vs = acc[i] * as_w, vd = acc[i] * ad_w;
    #pragma unroll
    for (int off2 = 32; off2; off2 >>= 1) {
      vs += __shfl_xor(vs, off2, 64);
      vd += __shfl_xor(vd, off2, 64);
    }
    if (lane == 0) { a_src[g * HEADS + head] = vs; a_dst[g * HEADS + head] = vd; }
  }
}

// ---------------- degree histogram (incl. self loops) ----------------
__global__ __launch_bounds__(256) void k_hist(const int* __restrict__ ei,
                                              int* __restrict__ count, int E, int N)
{
  int i = blockIdx.x * blockDim.x + threadIdx.x;
  int stride = gridDim.x * blockDim.x;
  for (int e = i; e < E; e += stride) atomicAdd(&count[ei[E + e]], 1);
  for (int n = i; n < N; n += stride) atomicAdd(&count[n], 1);   // self loop
}

// ---------------- 3-kernel exclusive scan over counts ----------------
__global__ __launch_bounds__(256) void k_scan1(const int* __restrict__ cnt,
                                               int* __restrict__ offs,
                                               int* __restrict__ bsum, int n)
{
  int t = threadIdx.x, b = blockIdx.x;
  int i = b * 256 + t;
  int v = (i < n) ? cnt[i] : 0;
  int sc = v;
  #pragma unroll
  for (int d2 = 1; d2 < 64; d2 <<= 1) {
    int u = __shfl_up(sc, d2, 64);
    if ((t & 63) >= d2) sc += u;
  }
  __shared__ int wsum[4];
  if ((t & 63) == 63) wsum[t >> 6] = sc;
  __syncthreads();
  int base = 0;
  for (int w = 0; w < (t >> 6); ++w) base += wsum[w];
  int incl = sc + base;
  if (i < n) offs[i] = incl - v;          // exclusive within block
  if (t == 255) bsum[b] = incl;           // block total
}

__global__ __launch_bounds__(256) void k_scan2(const int* __restrict__ bsum,
                                               int* __restrict__ bsumo, int nb)
{
  int t = threadIdx.x;
  int v = (t < nb) ? bsum[t] : 0;
  int sc = v;
  #pragma unroll
  for (int d2 = 1; d2 < 64; d2 <<= 1) {
    int u = __shfl_up(sc, d2, 64);
    if ((t & 63) >= d2) sc += u;
  }
  __shared__ int wsum[4];
  if ((t & 63) == 63) wsum[t >> 6] = sc;
  __syncthreads();
  int base = 0;
  for (int w = 0; w < (t >> 6); ++w) base += wsum[w];
  int incl = sc + base;
  if (t < nb) bsumo[t] = incl - v;        // exclusive block offsets
}

__global__ __launch_bounds__(256) void k_scan3(int* __restrict__ offs,
                                               const int* __restrict__ bsumo,
                                               int* __restrict__ cursor, int n, int total)
{
  int t = threadIdx.x, b = blockIdx.x;
  int i = b * 256 + t;
  if (i < n) {
    int o = offs[i] + bsumo[b];
    offs[i] = o;
    cursor[i] = o;
  }
  if (i == 0) offs[n] = total;
}

// ---------------- CSR scatter: src indices into dst-sorted slots ----------------
__global__ __launch_bounds__(256) void k_scatter(
    const int* __restrict__ ei, int* __restrict__ cursor,
    int* __restrict__ ssrc, int E, int N)
{
  int e = blockIdx.x * 256 + threadIdx.x;
  int tot = E + N;
  if (e >= tot) return;
  int s, d;
  if (e < E) { s = ei[e]; d = ei[E + e]; }
  else       { s = e - E; d = s; }        // self loop
  int pos = atomicAdd(&cursor[d], 1);
  ssrc[pos] = s;
}

// ---------------- aggregation: one WAVE per node; fused softmax+bias+ELU ----------------
// lane covers columns [4*lane, 4*lane+4); head = lane>>4.
__global__ __launch_bounds__(256) void k_agg(
    const unsigned short* __restrict__ h16, const int* __restrict__ offs,
    const int* __restrict__ ssrc,
    const float* __restrict__ a_src, const float* __restrict__ a_dst,
    const float* __restrict__ bias, const int* __restrict__ batch,
    unsigned short* __restrict__ outn, float* __restrict__ pooled, float* __restrict__ cntg,
    int N, int useAtomic)
{
  const int wid0 = blockIdx.x * WPB + (threadIdx.x >> 6);
  if (wid0 >= N) return;
  const int wid  = __builtin_amdgcn_readfirstlane(wid0);   // force wave-uniform -> s_loads
  const int lane = threadIdx.x & 63;
  const int head = lane >> 4;
  const int col  = lane << 2;

  const int beg = offs[wid], end = offs[wid + 1];
  const float ad = a_dst[wid * 4 + head];

  float4 acc = make_float4(0.f, 0.f, 0.f, 0.f);
  float den = 0.f;
  int k = beg;

  for (; k + 8 <= end; k += 8) {
    int s0 = ssrc[k + 0], s1 = ssrc[k + 1], s2 = ssrc[k + 2], s3 = ssrc[k + 3];
    int s4 = ssrc[k + 4], s5 = ssrc[k + 5], s6 = ssrc[k + 6], s7 = ssrc[k + 7];
    float e0 = a_src[s0 * 4 + head], e1 = a_src[s1 * 4 + head];
    float e2 = a_src[s2 * 4 + head], e3 = a_src[s3 * 4 + head];
    float e4 = a_src[s4 * 4 + head], e5 = a_src[s5 * 4 + head];
    float e6 = a_src[s6 * 4 + head], e7 = a_src[s7 * 4 + head];
    ushort4 h0 = *(const ushort4*)(h16 + (size_t)s0 * HIDDEN + col);
    ushort4 h1 = *(const ushort4*)(h16 + (size_t)s1 * HIDDEN + col);
    ushort4 h2 = *(const ushort4*)(h16 + (size_t)s2 * HIDDEN + col);
    ushort4 h3 = *(const ushort4*)(h16 + (size_t)s3 * HIDDEN + col);
    ushort4 h4 = *(const ushort4*)(h16 + (size_t)s4 * HIDDEN + col);
    ushort4 h5 = *(const ushort4*)(h16 + (size_t)s5 * HIDDEN + col);
    ushort4 h6 = *(const ushort4*)(h16 + (size_t)s6 * HIDDEN + col);
    ushort4 h7 = *(const ushort4*)(h16 + (size_t)s7 * HIDDEN + col);
    float w0, w1, w2, w3, w4, w5, w6, w7;
    e0 += ad; e0 = e0 > 0.f ? e0 : 0.2f * e0; w0 = __expf(e0);
    e1 += ad; e1 = e1 > 0.f ? e1 : 0.2f * e1; w1 = __expf(e1);
    e2 += ad; e2 = e2 > 0.f ? e2 : 0.2f * e2; w2 = __expf(e2);
    e3 += ad; e3 = e3 > 0.f ? e3 : 0.2f * e3; w3 = __expf(e3);
    e4 += ad; e4 = e4 > 0.f ? e4 : 0.2f * e4; w4 = __expf(e4);
    e5 += ad; e5 = e5 > 0.f ? e5 : 0.2f * e5; w5 = __expf(e5);
    e6 += ad; e6 = e6 > 0.f ? e6 : 0.2f * e6; w6 = __expf(e6);
    e7 += ad; e7 = e7 > 0.f ? e7 : 0.2f * e7; w7 = __expf(e7);
    den += ((w0 + w1) + (w2 + w3)) + ((w4 + w5) + (w6 + w7));
    acc.x = fmaf(bf2f(h0.x), w0, acc.x); acc.y = fmaf(bf2f(h0.y), w0, acc.y);
    acc.z = fmaf(bf2f(h0.z), w0, acc.z); acc.w = fmaf(bf2f(h0.w), w0, acc.w);
    acc.x = fmaf(bf2f(h1.x), w1, acc.x); acc.y = fmaf(bf2f(h1.y), w1, acc.y);
    acc.z = fmaf(bf2f(h1.z), w1, acc.z); acc.w = fmaf(bf2f(h1.w), w1, acc.w);
    acc.x = fmaf(bf2f(h2.x), w2, acc.x); acc.y = fmaf(bf2f(h2.y), w2, acc.y);
    acc.z = fmaf(bf2f(h2.z), w2, acc.z); acc.w = fmaf(bf2f(h2.w), w2, acc.w);
    acc.x = fmaf(bf2f(h3.x), w3, acc.x); acc.y = fmaf(bf2f(h3.y), w3, acc.y);
    acc.z = fmaf(bf2f(h3.z), w3, acc.z); acc.w = fmaf(bf2f(h3.w), w3, acc.w);
    acc.x = fmaf(bf2f(h4.x), w4, acc.x); acc.y = fmaf(bf2f(h4.y), w4, acc.y);
    acc.z = fmaf(bf2f(h4.z), w4, acc.z); acc.w = fmaf(bf2f(h4.w), w4, acc.w);
    acc.x = fmaf(bf2f(h5.x), w5, acc.x); acc.y = fmaf(bf2f(h5.y), w5, acc.y);
    acc.z = fmaf(bf2f(h5.z), w5, acc.z); acc.w = fmaf(bf2f(h5.w), w5, acc.w);
    acc.x = fmaf(bf2f(h6.x), w6, acc.x); acc.y = fmaf(bf2f(h6.y), w6, acc.y);
    acc.z = fmaf(bf2f(h6.z), w6, acc.z); acc.w = fmaf(bf2f(h6.w), w6, acc.w);
    acc.x = fmaf(bf2f(h7.x), w7, acc.x); acc.y = fmaf(bf2f(h7.y), w7, acc.y);
    acc.z = fmaf(bf2f(h7.z), w7, acc.z); acc.w = fmaf(bf2f(h7.w), w7, acc.w);
  }
  for (; k < end; ++k) {
    int s = ssrc[k];
    float e = a_src[s * 4 + head] + ad;
    e = e > 0.f ? e : 0.2f * e;
    float w = __expf(e);
    ushort4 hv = *(const ushort4*)(h16 + (size_t)s * HIDDEN + col);
    den += w;
    acc.x = fmaf(bf2f(hv.x), w, acc.x); acc.y = fmaf(bf2f(hv.y), w, acc.y);
    acc.z = fmaf(bf2f(hv.z), w, acc.z); acc.w = fmaf(bf2f(hv.w), w, acc.w);
  }

  const float inv = 1.f / den;          // den > 0 guaranteed by self loop
  float4 bv = *(const float4*)&bias[col];
  float4 o;
  o.x = fmaf(acc.x, inv, bv.x); o.x = o.x > 0.f ? o.x : expm1f(o.x);
  o.y = fmaf(acc.y, inv, bv.y); o.y = o.y > 0.f ? o.y : expm1f(o.y);
  o.z = fmaf(acc.z, inv, bv.z); o.z = o.z > 0.f ? o.z : expm1f(o.z);
  o.w = fmaf(acc.w, inv, bv.w); o.w = o.w > 0.f ? o.w : expm1f(o.w);

  if (useAtomic) {
    int g = batch[wid];
    atomicAdd(&pooled[g * HIDDEN + col + 0], o.x);
    atomicAdd(&pooled[g * HIDDEN + col + 1], o.y);
    atomicAdd(&pooled[g * HIDDEN + col + 2], o.z);
    atomicAdd(&pooled[g * HIDDEN + col + 3], o.w);
    if (lane == 0) atomicAdd(&cntg[g], 1.0f);
  } else {
    ushort4 ov;
    ov.x = f2bf(o.x);
    ov.y = f2bf(o.y);
    ov.z = f2bf(o.z);
    ov.w = f2bf(o.w);
    *(ushort4*)(outn + (size_t)wid * HIDDEN + col) = ov;
  }
}

// ---------------- per-graph mean pool + fused FC (no atomics) ----------------
__global__ __launch_bounds__(256) void k_pool(
    const unsigned short* __restrict__ outn, const int* __restrict__ batch,
    const float* __restrict__ fc_w, const float* __restrict__ fc_b,
    float* __restrict__ out, int N)
{
  const int g = blockIdx.x, t = threadIdx.x;
  // binary search: node range [lo,hi) of graph g (batch is sorted)
  int a = 0, b = N;
  while (a < b) { int m = (a + b) >> 1; if (batch[m] < g) a = m + 1; else b = m; }
  const int lo = a;
  b = N;
  while (a < b) { int m = (a + b) >> 1; if (batch[m] < g + 1) a = m + 1; else b = m; }
  const int hi = a;

  float acc = 0.f, acc2 = 0.f;
  int n = lo;
  for (; n + 2 <= hi; n += 2) {
    acc  += bf2f(outn[(size_t)n * HIDDEN + t]);
    acc2 += bf2f(outn[(size_t)(n + 1) * HIDDEN + t]);
  }
  if (n < hi) acc += bf2f(outn[(size_t)n * HIDDEN + t]);
  acc += acc2;

  float cnt = (float)(hi - lo);
  float pooledv = acc / fmaxf(cnt, 1.0f);
  float v = pooledv * fc_w[t];
  #pragma unroll
  for (int off2 = 32; off2; off2 >>= 1) v += __shfl_xor(v, off2, 64);
  __shared__ float ws4[4];
  if ((t & 63) == 0) ws4[t >> 6] = v;
  __syncthreads();
  if (t == 0) out[g] = ws4[0] + ws4[1] + ws4[2] + ws4[3] + fc_b[0];
}

// ---------------- fallback final: mean pool + FC from atomic-pooled ----------------
__global__ __launch_bounds__(64) void k_fc(
    const float* __restrict__ pooled, const float* __restrict__ cntg,
    const float* __restrict__ fc_w, const float* __restrict__ fc_b, float* __restrict__ out)
{
  int g = blockIdx.x, l = threadIdx.x;
  float acc = 0.f;
  for (int j = l; j < HIDDEN; j += 64) acc += pooled[g * HIDDEN + j] * fc_w[j];
  #pragma unroll
  for (int off2 = 32; off2; off2 >>= 1) acc += __shfl_xor(acc, off2, 64);
  if (l == 0) out[g] = acc / fmaxf(cntg[g], 1.0f) + fc_b[0];
}

extern "C" void kernel_launch(void* const* d_in, const int* in_sizes, int n_in,
                              void* d_out, int out_size, void* d_ws, size_t ws_size,
                              hipStream_t stream)
{
  const float* x     = (const float*)d_in[0];
  const int*   ei    = (const int*)  d_in[1];   // [2,E] flat: [0..E)=src, [E..2E)=dst
  /* d_in[2] edge_attr: unused by reference */
  const int*   batch = (const int*)  d_in[3];
  const float* W     = (const float*)d_in[4];
  const float* att_s = (const float*)d_in[5];
  const float* att_d = (const float*)d_in[6];
  const float* bias  = (const float*)d_in[7];
  const float* fc_w  = (const float*)d_in[8];
  const float* fc_b  = (const float*)d_in[9];
  float* out = (float*)d_out;

  const int N   = in_sizes[0] / FIN;
  const int E   = in_sizes[1] / 2;
  const int TOT = E + N;

  char* p = (char*)d_ws;
  size_t o = 0;
  auto alloc = [&](size_t bytes) -> void* {
    void* r = p + o;
    o = (o + bytes + 255) & ~(size_t)255;
    return r;
  };
  // zero-init region first: one memset covers [count | pooled | cntg]
  int*   count  = (int*)  alloc((size_t)N * sizeof(int));
  float* pooled = (float*)alloc((size_t)NGRAPH * HIDDEN * sizeof(float));
  float* cntg   = (float*)alloc((size_t)NGRAPH * sizeof(float));
  size_t zeroBytes = o;
  unsigned short* h16 = (unsigned short*)alloc((size_t)N * HIDDEN * sizeof(unsigned short));
  float* a_src  = (float*)alloc((size_t)N * 4 * sizeof(float));
  float* a_dst  = (float*)alloc((size_t)N * 4 * sizeof(float));
  int*   offs   = (int*)  alloc((size_t)(N + 1) * sizeof(int));
  int*   cursor = (int*)  alloc((size_t)N * sizeof(int));
  int*   bsum   = (int*)  alloc(1024);
  int*   bsumo  = (int*)  alloc(1024);
  int*   ssrc   = (int*)  alloc((size_t)TOT * sizeof(int));
  unsigned short* outn = (unsigned short*)alloc((size_t)N * HIDDEN * sizeof(unsigned short));
  const int useAtomic = (o > ws_size) ? 1 : 0;   // fall back if ws too small
  (void)n_in; (void)out_size;

  (void)hipMemsetAsync(d_ws, 0, zeroBytes, stream);

  int gemmBlocks = (N + NPB - 1) / NPB;
  hipLaunchKernelGGL(k_gemm, dim3(gemmBlocks), dim3(256), 0, stream,
                     x, W, att_s, att_d, h16, a_src, a_dst, N);
  hipLaunchKernelGGL(k_hist, dim3(2048), dim3(256), 0, stream, ei, count, E, N);
  int sb = (N + 255) / 256;
  hipLaunchKernelGGL(k_scan1, dim3(sb), dim3(256), 0, stream, count, offs, bsum, N);
  hipLaunchKernelGGL(k_scan2, dim3(1), dim3(256), 0, stream, bsum, bsumo, sb);
  hipLaunchKernelGGL(k_scan3, dim3(sb), dim3(256), 0, stream, offs, bsumo, cursor, N, TOT);
  hipLaunchKernelGGL(k_scatter, dim3((TOT + 255) / 256), dim3(256), 0, stream,
                     ei, cursor, ssrc, E, N);
  hipLaunchKernelGGL(k_agg, dim3((N + WPB - 1) / WPB), dim3(256), 0, stream,
                     h16, offs, ssrc, a_src, a_dst, bias, batch,
                     outn, pooled, cntg, N, useAtomic);
  if (useAtomic) {
    hipLaunchKernelGGL(k_fc, dim3(NGRAPH), dim3(64), 0, stream,
                       pooled, cntg, fc_w, fc_b, out);
  } else {
    hipLaunchKernelGGL(k_pool, dim3(NGRAPH), dim3(256), 0, stream,
                       outn, batch, fc_w, fc_b, out, N);
  }
}

// Round 5
// 308.364 us; speedup vs baseline: 2.4696x; 1.2453x over previous
//
#include <hip/hip_runtime.h>
#include <hip/hip_bf16.h>
#include <math.h>

#define HEADS   4
#define HIDDEN  256
#define FIN     128
#define NGRAPH  256
#define WPB     4    // waves (=nodes) per block in k_agg

using frag_ab = __attribute__((ext_vector_type(8))) short;   // 8 bf16 (4 VGPRs)
using frag_cd = __attribute__((ext_vector_type(4))) float;   // 4 fp32

__device__ __forceinline__ float bf2f(unsigned short u) {
  union { unsigned int i; float f; } v; v.i = ((unsigned int)u) << 16; return v.f;
}
__device__ __forceinline__ unsigned short f2bf(float f) {
  union { float f; unsigned int i; } v; v.f = f;
  unsigned int b = v.i;
  b += 0x7FFFu + ((b >> 16) & 1u);   // round-to-nearest-even
  return (unsigned short)(b >> 16);
}

// ---------------- prep: W (fp32 [128][256]) -> bf16 MFMA-B-fragment order ----------------
// Bf[((nfg*4 + ks)*64 + lane)*8 + j] = bf16(W[ks*32 + (lane>>4)*8 + j][nfg*16 + (lane&15)])
__global__ __launch_bounds__(256) void k_prep(const float* __restrict__ W,
                                              unsigned short* __restrict__ Bf)
{
  int id = blockIdx.x * 256 + threadIdx.x;      // 0..4095
  if (id >= 16 * 4 * 64) return;
  int l = id & 63, ks = (id >> 6) & 3, nfg = id >> 8;
  int col = nfg * 16 + (l & 15);
  int k0  = ks * 32 + (l >> 4) * 8;
  unsigned short v[8];
  #pragma unroll
  for (int j = 0; j < 8; ++j) v[j] = f2bf(W[(k0 + j) * HIDDEN + col]);
  *(uint4*)(Bf + (size_t)id * 8) = *(const uint4*)v;
}

// ---------------- MFMA GEMM: h = bf16(x) @ bf16(W), fp32 accum; + attention dots ----------------
// block: 256 thr = 4 waves; 32 rows/block; wave w covers cols [w*64, w*64+64) (== head w)
__global__ __launch_bounds__(256) void k_gemm(
    const float* __restrict__ x, const unsigned short* __restrict__ Bf,
    const float* __restrict__ att_s, const float* __restrict__ att_d,
    unsigned short* __restrict__ h16, float* __restrict__ a_src, float* __restrict__ a_dst,
    int nNodes)
{
  __shared__ unsigned short As[32 * FIN];       // 8 KB, XOR-swizzled
  const int t  = threadIdx.x;
  const int n0 = blockIdx.x * 32;

  // ---- stage x tile (fp32 -> bf16) into LDS with (row&7)<<4 byte-XOR swizzle ----
  {
    const int row = t >> 3;                     // 0..31
    const int g   = n0 + row;
    const int c0  = (t & 7) * 16;               // float offset in row
    float4 f0, f1, f2, f3;
    if (g < nNodes) {
      const float* xr = x + (size_t)g * FIN + c0;
      f0 = *(const float4*)(xr + 0);  f1 = *(const float4*)(xr + 4);
      f2 = *(const float4*)(xr + 8);  f3 = *(const float4*)(xr + 12);
    } else {
      f0 = f1 = f2 = f3 = make_float4(0.f, 0.f, 0.f, 0.f);
    }
    unsigned short u[16];
    u[0]=f2bf(f0.x); u[1]=f2bf(f0.y); u[2]=f2bf(f0.z); u[3]=f2bf(f0.w);
    u[4]=f2bf(f1.x); u[5]=f2bf(f1.y); u[6]=f2bf(f1.z); u[7]=f2bf(f1.w);
    u[8]=f2bf(f2.x); u[9]=f2bf(f2.y); u[10]=f2bf(f2.z); u[11]=f2bf(f2.w);
    u[12]=f2bf(f3.x); u[13]=f2bf(f3.y); u[14]=f2bf(f3.z); u[15]=f2bf(f3.w);
    const int sw = (row & 7) << 4;
    char* base = (char*)As + row * 256;
    *(uint4*)(base + (((t & 7) * 32)      ^ sw)) = *(const uint4*)(u + 0);
    *(uint4*)(base + (((t & 7) * 32 + 16) ^ sw)) = *(const uint4*)(u + 8);
  }
  __syncthreads();

  const int w    = t >> 6;                      // wave == head
  const int l    = t & 63;
  const int lrow = l & 15;

  // ---- B fragments: contiguous 16B per lane from Bf (L2-hot) ----
  frag_ab bfr[4][4];                            // [nf][ks]
  #pragma unroll
  for (int nf = 0; nf < 4; ++nf)
    #pragma unroll
    for (int ks = 0; ks < 4; ++ks)
      bfr[nf][ks] = *(const frag_ab*)(Bf + (size_t)(((w * 4 + nf) * 4 + ks) * 64 + l) * 8);

  // ---- A fragments from swizzled LDS ----
  frag_ab afr[2][4];                            // [mf][ks]
  const int lsw = (lrow & 7) << 4;
  #pragma unroll
  for (int mf = 0; mf < 2; ++mf)
    #pragma unroll
    for (int ks = 0; ks < 4; ++ks) {
      int byte = (mf * 16 + lrow) * 256 + ((ks * 64 + (l >> 4) * 16) ^ lsw);
      afr[mf][ks] = *(const frag_ab*)((const char*)As + byte);
    }

  // ---- 32 MFMAs: acc[mf][nf] += A[mf][ks] * B[nf][ks] over ks ----
  frag_cd acc[2][4];
  #pragma unroll
  for (int mf = 0; mf < 2; ++mf)
    #pragma unroll
    for (int nf = 0; nf < 4; ++nf)
      acc[mf][nf] = (frag_cd){0.f, 0.f, 0.f, 0.f};
  #pragma unroll
  for (int ks = 0; ks < 4; ++ks)
    #pragma unroll
    for (int mf = 0; mf < 2; ++mf)
      #pragma unroll
      for (int nf = 0; nf < 4; ++nf)
        acc[mf][nf] = __builtin_amdgcn_mfma_f32_16x16x32_bf16(
            afr[mf][ks], bfr[nf][ks], acc[mf][nf], 0, 0, 0);

  // ---- epilogue: h16 store + attention dots ----
  float asw[4], adw[4];
  #pragma unroll
  for (int nf = 0; nf < 4; ++nf) {
    asw[nf] = att_s[w * 64 + nf * 16 + lrow];
    adw[nf] = att_d[w * 64 + nf * 16 + lrow];
  }

  #pragma unroll
  for (int mf = 0; mf < 2; ++mf) {
    #pragma unroll
    for (int r = 0; r < 4; ++r) {
      const int rowg = n0 + mf * 16 + (l >> 4) * 4 + r;
      // h store (col = w*64 + nf*16 + lrow; consecutive lanes -> consecutive cols)
      if (rowg < nNodes) {
        #pragma unroll
        for (int nf = 0; nf < 4; ++nf)
          h16[(size_t)rowg * HIDDEN + w * 64 + nf * 16 + lrow] = f2bf(acc[mf][nf][r]);
      }
      // attention dots: row-sum over this head's 64 cols
      float ss = 0.f, sd = 0.f;
      #pragma unroll
      for (int nf = 0; nf < 4; ++nf) {
        ss = fmaf(acc[mf][nf][r], asw[nf], ss);
        sd = fmaf(acc[mf][nf][r], adw[nf], sd);
      }
      #pragma unroll
      for (int off2 = 1; off2 <= 8; off2 <<= 1) {
        ss += __shfl_xor(ss, off2, 64);
        sd += __shfl_xor(sd, off2, 64);
      }
      if (lrow == 0 && rowg < nNodes) {
        a_src[rowg * HEADS + w] = ss;
        a_dst[rowg * HEADS + w] = sd;
      }
    }
  }
}

// ---------------- degree histogram (incl. self loops) ----------------
__global__ __launch_bounds__(256) void k_hist(const int* __restrict__ ei,
                                              int* __restrict__ count, int E, int N)
{
  int i = blockIdx.x * blockDim.x + threadIdx.x;
  int stride = gridDim.x * blockDim.x;
  for (int e = i; e < E; e += stride) atomicAdd(&count[ei[E + e]], 1);
  for (int n = i; n < N; n += stride) atomicAdd(&count[n], 1);   // self loop
}

// ---------------- 3-kernel exclusive scan over counts ----------------
__global__ __launch_bounds__(256) void k_scan1(const int* __restrict__ cnt,
                                               int* __restrict__ offs,
                                               int* __restrict__ bsum, int n)
{
  int t = threadIdx.x, b = blockIdx.x;
  int i = b * 256 + t;
  int v = (i < n) ? cnt[i] : 0;
  int sc = v;
  #pragma unroll
  for (int d2 = 1; d2 < 64; d2 <<= 1) {
    int u = __shfl_up(sc, d2, 64);
    if ((t & 63) >= d2) sc += u;
  }
  __shared__ int wsum[4];
  if ((t & 63) == 63) wsum[t >> 6] = sc;
  __syncthreads();
  int base = 0;
  for (int w = 0; w < (t >> 6); ++w) base += wsum[w];
  int incl = sc + base;
  if (i < n) offs[i] = incl - v;          // exclusive within block
  if (t == 255) bsum[b] = incl;           // block total
}

__global__ __launch_bounds__(256) void k_scan2(const int* __restrict__ bsum,
                                               int* __restrict__ bsumo, int nb)
{
  int t = threadIdx.x;
  int v = (t < nb) ? bsum[t] : 0;
  int sc = v;
  #pragma unroll
  for (int d2 = 1; d2 < 64; d2 <<= 1) {
    int u = __shfl_up(sc, d2, 64);
    if ((t & 63) >= d2) sc += u;
  }
  __shared__ int wsum[4];
  if ((t & 63) == 63) wsum[t >> 6] = sc;
  __syncthreads();
  int base = 0;
  for (int w = 0; w < (t >> 6); ++w) base += wsum[w];
  int incl = sc + base;
  if (t < nb) bsumo[t] = incl - v;        // exclusive block offsets
}

__global__ __launch_bounds__(256) void k_scan3(int* __restrict__ offs,
                                               const int* __restrict__ bsumo,
                                               int* __restrict__ cursor, int n, int total)
{
  int t = threadIdx.x, b = blockIdx.x;
  int i = b * 256 + t;
  if (i < n) {
    int o = offs[i] + bsumo[b];
    offs[i] = o;
    cursor[i] = o;
  }
  if (i == 0) offs[n] = total;
}

// ---------------- CSR scatter: src indices into dst-sorted slots ----------------
__global__ __launch_bounds__(256) void k_scatter(
    const int* __restrict__ ei, int* __restrict__ cursor,
    int* __restrict__ ssrc, int E, int N)
{
  int e = blockIdx.x * 256 + threadIdx.x;
  int tot = E + N;
  if (e >= tot) return;
  int s, d;
  if (e < E) { s = ei[e]; d = ei[E + e]; }
  else       { s = e - E; d = s; }        // self loop
  int pos = atomicAdd(&cursor[d], 1);
  ssrc[pos] = s;
}

// ---------------- aggregation: one WAVE per node; fused softmax+bias+ELU ----------------
// lane covers columns [4*lane, 4*lane+4); head = lane>>4.
__global__ __launch_bounds__(256) void k_agg(
    const unsigned short* __restrict__ h16, const int* __restrict__ offs,
    const int* __restrict__ ssrc,
    const float* __restrict__ a_src, const float* __restrict__ a_dst,
    const float* __restrict__ bias, const int* __restrict__ batch,
    unsigned short* __restrict__ outn, float* __restrict__ pooled, float* __restrict__ cntg,
    int N, int useAtomic)
{
  const int wid0 = blockIdx.x * WPB + (threadIdx.x >> 6);
  if (wid0 >= N) return;
  const int wid  = __builtin_amdgcn_readfirstlane(wid0);   // force wave-uniform -> s_loads
  const int lane = threadIdx.x & 63;
  const int head = lane >> 4;
  const int col  = lane << 2;

  const int beg = offs[wid], end = offs[wid + 1];
  const float ad = a_dst[wid * 4 + head];

  float4 acc = make_float4(0.f, 0.f, 0.f, 0.f);
  float den = 0.f;
  int k = beg;

  for (; k + 8 <= end; k += 8) {
    int s0 = ssrc[k + 0], s1 = ssrc[k + 1], s2 = ssrc[k + 2], s3 = ssrc[k + 3];
    int s4 = ssrc[k + 4], s5 = ssrc[k + 5], s6 = ssrc[k + 6], s7 = ssrc[k + 7];
    float e0 = a_src[s0 * 4 + head], e1 = a_src[s1 * 4 + head];
    float e2 = a_src[s2 * 4 + head], e3 = a_src[s3 * 4 + head];
    float e4 = a_src[s4 * 4 + head], e5 = a_src[s5 * 4 + head];
    float e6 = a_src[s6 * 4 + head], e7 = a_src[s7 * 4 + head];
    ushort4 h0 = *(const ushort4*)(h16 + (size_t)s0 * HIDDEN + col);
    ushort4 h1 = *(const ushort4*)(h16 + (size_t)s1 * HIDDEN + col);
    ushort4 h2 = *(const ushort4*)(h16 + (size_t)s2 * HIDDEN + col);
    ushort4 h3 = *(const ushort4*)(h16 + (size_t)s3 * HIDDEN + col);
    ushort4 h4 = *(const ushort4*)(h16 + (size_t)s4 * HIDDEN + col);
    ushort4 h5 = *(const ushort4*)(h16 + (size_t)s5 * HIDDEN + col);
    ushort4 h6 = *(const ushort4*)(h16 + (size_t)s6 * HIDDEN + col);
    ushort4 h7 = *(const ushort4*)(h16 + (size_t)s7 * HIDDEN + col);
    float w0, w1, w2, w3, w4, w5, w6, w7;
    e0 += ad; e0 = e0 > 0.f ? e0 : 0.2f * e0; w0 = __expf(e0);
    e1 += ad; e1 = e1 > 0.f ? e1 : 0.2f * e1; w1 = __expf(e1);
    e2 += ad; e2 = e2 > 0.f ? e2 : 0.2f * e2; w2 = __expf(e2);
    e3 += ad; e3 = e3 > 0.f ? e3 : 0.2f * e3; w3 = __expf(e3);
    e4 += ad; e4 = e4 > 0.f ? e4 : 0.2f * e4; w4 = __expf(e4);
    e5 += ad; e5 = e5 > 0.f ? e5 : 0.2f * e5; w5 = __expf(e5);
    e6 += ad; e6 = e6 > 0.f ? e6 : 0.2f * e6; w6 = __expf(e6);
    e7 += ad; e7 = e7 > 0.f ? e7 : 0.2f * e7; w7 = __expf(e7);
    den += ((w0 + w1) + (w2 + w3)) + ((w4 + w5) + (w6 + w7));
    acc.x = fmaf(bf2f(h0.x), w0, acc.x); acc.y = fmaf(bf2f(h0.y), w0, acc.y);
    acc.z = fmaf(bf2f(h0.z), w0, acc.z); acc.w = fmaf(bf2f(h0.w), w0, acc.w);
    acc.x = fmaf(bf2f(h1.x), w1, acc.x); acc.y = fmaf(bf2f(h1.y), w1, acc.y);
    acc.z = fmaf(bf2f(h1.z), w1, acc.z); acc.w = fmaf(bf2f(h1.w), w1, acc.w);
    acc.x = fmaf(bf2f(h2.x), w2, acc.x); acc.y = fmaf(bf2f(h2.y), w2, acc.y);
    acc.z = fmaf(bf2f(h2.z), w2, acc.z); acc.w = fmaf(bf2f(h2.w), w2, acc.w);
    acc.x = fmaf(bf2f(h3.x), w3, acc.x); acc.y = fmaf(bf2f(h3.y), w3, acc.y);
    acc.z = fmaf(bf2f(h3.z), w3, acc.z); acc.w = fmaf(bf2f(h3.w), w3, acc.w);
    acc.x = fmaf(bf2f(h4.x), w4, acc.x); acc.y = fmaf(bf2f(h4.y), w4, acc.y);
    acc.z = fmaf(bf2f(h4.z), w4, acc.z); acc.w = fmaf(bf2f(h4.w), w4, acc.w);
    acc.x = fmaf(bf2f(h5.x), w5, acc.x); acc.y = fmaf(bf2f(h5.y), w5, acc.y);
    acc.z = fmaf(bf2f(h5.z), w5, acc.z); acc.w = fmaf(bf2f(h5.w), w5, acc.w);
    acc.x = fmaf(bf2f(h6.x), w6, acc.x); acc.y = fmaf(bf2f(h6.y), w6, acc.y);
    acc.z = fmaf(bf2f(h6.z), w6, acc.z); acc.w = fmaf(bf2f(h6.w), w6, acc.w);
    acc.x = fmaf(bf2f(h7.x), w7, acc.x); acc.y = fmaf(bf2f(h7.y), w7, acc.y);
    acc.z = fmaf(bf2f(h7.z), w7, acc.z); acc.w = fmaf(bf2f(h7.w), w7, acc.w);
  }
  for (; k < end; ++k) {
    int s = ssrc[k];
    float e = a_src[s * 4 + head] + ad;
    e = e > 0.f ? e : 0.2f * e;
    float w = __expf(e);
    ushort4 hv = *(const ushort4*)(h16 + (size_t)s * HIDDEN + col);
    den += w;
    acc.x = fmaf(bf2f(hv.x), w, acc.x); acc.y = fmaf(bf2f(hv.y), w, acc.y);
    acc.z = fmaf(bf2f(hv.z), w, acc.z); acc.w = fmaf(bf2f(hv.w), w, acc.w);
  }

  const float inv = 1.f / den;          // den > 0 guaranteed by self loop
  float4 bv = *(const float4*)&bias[col];
  float4 o;
  o.x = fmaf(acc.x, inv, bv.x); o.x = o.x > 0.f ? o.x : expm1f(o.x);
  o.y = fmaf(acc.y, inv, bv.y); o.y = o.y > 0.f ? o.y : expm1f(o.y);
  o.z = fmaf(acc.z, inv, bv.z); o.z = o.z > 0.f ? o.z : expm1f(o.z);
  o.w = fmaf(acc.w, inv, bv.w); o.w = o.w > 0.f ? o.w : expm1f(o.w);

  if (useAtomic) {
    int g = batch[wid];
    atomicAdd(&pooled[g * HIDDEN + col + 0], o.x);
    atomicAdd(&pooled[g * HIDDEN + col + 1], o.y);
    atomicAdd(&pooled[g * HIDDEN + col + 2], o.z);
    atomicAdd(&pooled[g * HIDDEN + col + 3], o.w);
    if (lane == 0) atomicAdd(&cntg[g], 1.0f);
  } else {
    ushort4 ov;
    ov.x = f2bf(o.x);
    ov.y = f2bf(o.y);
    ov.z = f2bf(o.z);
    ov.w = f2bf(o.w);
    *(ushort4*)(outn + (size_t)wid * HIDDEN + col) = ov;
  }
}

// ---------------- per-graph mean pool + fused FC (no atomics) ----------------
__global__ __launch_bounds__(256) void k_pool(
    const unsigned short* __restrict__ outn, const int* __restrict__ batch,
    const float* __restrict__ fc_w, const float* __restrict__ fc_b,
    float* __restrict__ out, int N)
{
  const int g = blockIdx.x, t = threadIdx.x;
  // binary search: node range [lo,hi) of graph g (batch is sorted)
  int a = 0, b = N;
  while (a < b) { int m = (a + b) >> 1; if (batch[m] < g) a = m + 1; else b = m; }
  const int lo = a;
  b = N;
  while (a < b) { int m = (a + b) >> 1; if (batch[m] < g + 1) a = m + 1; else b = m; }
  const int hi = a;

  float acc = 0.f, acc2 = 0.f;
  int n = lo;
  for (; n + 2 <= hi; n += 2) {
    acc  += bf2f(outn[(size_t)n * HIDDEN + t]);
    acc2 += bf2f(outn[(size_t)(n + 1) * HIDDEN + t]);
  }
  if (n < hi) acc += bf2f(outn[(size_t)n * HIDDEN + t]);
  acc += acc2;

  float cnt = (float)(hi - lo);
  float pooledv = acc / fmaxf(cnt, 1.0f);
  float v = pooledv * fc_w[t];
  #pragma unroll
  for (int off2 = 32; off2; off2 >>= 1) v += __shfl_xor(v, off2, 64);
  __shared__ float ws4[4];
  if ((t & 63) == 0) ws4[t >> 6] = v;
  __syncthreads();
  if (t == 0) out[g] = ws4[0] + ws4[1] + ws4[2] + ws4[3] + fc_b[0];
}

// ---------------- fallback final: mean pool + FC from atomic-pooled ----------------
__global__ __launch_bounds__(64) void k_fc(
    const float* __restrict__ pooled, const float* __restrict__ cntg,
    const float* __restrict__ fc_w, const float* __restrict__ fc_b, float* __restrict__ out)
{
  int g = blockIdx.x, l = threadIdx.x;
  float acc = 0.f;
  for (int j = l; j < HIDDEN; j += 64) acc += pooled[g * HIDDEN + j] * fc_w[j];
  #pragma unroll
  for (int off2 = 32; off2; off2 >>= 1) acc += __shfl_xor(acc, off2, 64);
  if (l == 0) out[g] = acc / fmaxf(cntg[g], 1.0f) + fc_b[0];
}

extern "C" void kernel_launch(void* const* d_in, const int* in_sizes, int n_in,
                              void* d_out, int out_size, void* d_ws, size_t ws_size,
                              hipStream_t stream)
{
  const float* x     = (const float*)d_in[0];
  const int*   ei    = (const int*)  d_in[1];   // [2,E] flat: [0..E)=src, [E..2E)=dst
  /* d_in[2] edge_attr: unused by reference */
  const int*   batch = (const int*)  d_in[3];
  const float* W     = (const float*)d_in[4];
  const float* att_s = (const float*)d_in[5];
  const float* att_d = (const float*)d_in[6];
  const float* bias  = (const float*)d_in[7];
  const float* fc_w  = (const float*)d_in[8];
  const float* fc_b  = (const float*)d_in[9];
  float* out = (float*)d_out;

  const int N   = in_sizes[0] / FIN;
  const int E   = in_sizes[1] / 2;
  const int TOT = E + N;

  char* p = (char*)d_ws;
  size_t o = 0;
  auto alloc = [&](size_t bytes) -> void* {
    void* r = p + o;
    o = (o + bytes + 255) & ~(size_t)255;
    return r;
  };
  // zero-init region first: one memset covers [count | pooled | cntg]
  int*   count  = (int*)  alloc((size_t)N * sizeof(int));
  float* pooled = (float*)alloc((size_t)NGRAPH * HIDDEN * sizeof(float));
  float* cntg   = (float*)alloc((size_t)NGRAPH * sizeof(float));
  size_t zeroBytes = o;
  unsigned short* h16 = (unsigned short*)alloc((size_t)N * HIDDEN * sizeof(unsigned short));
  unsigned short* Bf  = (unsigned short*)alloc((size_t)FIN * HIDDEN * sizeof(unsigned short));
  float* a_src  = (float*)alloc((size_t)N * 4 * sizeof(float));
  float* a_dst  = (float*)alloc((size_t)N * 4 * sizeof(float));
  int*   offs   = (int*)  alloc((size_t)(N + 1) * sizeof(int));
  int*   cursor = (int*)  alloc((size_t)N * sizeof(int));
  int*   bsum   = (int*)  alloc(1024);
  int*   bsumo  = (int*)  alloc(1024);
  int*   ssrc   = (int*)  alloc((size_t)TOT * sizeof(int));
  unsigned short* outn = (unsigned short*)alloc((size_t)N * HIDDEN * sizeof(unsigned short));
  const int useAtomic = (o > ws_size) ? 1 : 0;   // fall back if ws too small
  (void)n_in; (void)out_size;

  (void)hipMemsetAsync(d_ws, 0, zeroBytes, stream);

  hipLaunchKernelGGL(k_prep, dim3(16), dim3(256), 0, stream, W, Bf);
  hipLaunchKernelGGL(k_gemm, dim3((N + 31) / 32), dim3(256), 0, stream,
                     x, Bf, att_s, att_d, h16, a_src, a_dst, N);
  hipLaunchKernelGGL(k_hist, dim3(2048), dim3(256), 0, stream, ei, count, E, N);
  int sb = (N + 255) / 256;
  hipLaunchKernelGGL(k_scan1, dim3(sb), dim3(256), 0, stream, count, offs, bsum, N);
  hipLaunchKernelGGL(k_scan2, dim3(1), dim3(256), 0, stream, bsum, bsumo, sb);
  hipLaunchKernelGGL(k_scan3, dim3(sb), dim3(256), 0, stream, offs, bsumo, cursor, N, TOT);
  hipLaunchKernelGGL(k_scatter, dim3((TOT + 255) / 256), dim3(256), 0, stream,
                     ei, cursor, ssrc, E, N);
  hipLaunchKernelGGL(k_agg, dim3((N + WPB - 1) / WPB), dim3(256), 0, stream,
                     h16, offs, ssrc, a_src, a_dst, bias, batch,
                     outn, pooled, cntg, N, useAtomic);
  if (useAtomic) {
    hipLaunchKernelGGL(k_fc, dim3(NGRAPH), dim3(64), 0, stream,
                       pooled, cntg, fc_w, fc_b, out);
  } else {
    hipLaunchKernelGGL(k_pool, dim3(NGRAPH), dim3(256), 0, stream,
                       outn, batch, fc_w, fc_b, out, N);
  }
}

// Round 6
// 276.865 us; speedup vs baseline: 2.7506x; 1.1138x over previous
//
#include <hip/hip_runtime.h>
#include <hip/hip_bf16.h>
#include <math.h>

#define HEADS   4
#define HIDDEN  256
#define FIN     128
#define NGRAPH  256
#define WPB     4    // waves (=nodes) per block in k_agg
#define HISTB   512  // hist blocks appended to gemm grid
#define PCHUNK  64   // nodes per block in k_poolp

using frag_ab = __attribute__((ext_vector_type(8))) short;   // 8 bf16 (4 VGPRs)
using frag_cd = __attribute__((ext_vector_type(4))) float;   // 4 fp32

__device__ __forceinline__ float bf2f(unsigned short u) {
  union { unsigned int i; float f; } v; v.i = ((unsigned int)u) << 16; return v.f;
}
__device__ __forceinline__ unsigned short f2bf(float f) {
  union { float f; unsigned int i; } v; v.f = f;
  unsigned int b = v.i;
  b += 0x7FFFu + ((b >> 16) & 1u);   // round-to-nearest-even
  return (unsigned short)(b >> 16);
}

// ---------------- prep: W (fp32 [128][256]) -> bf16 MFMA-B-fragment order ----------------
__global__ __launch_bounds__(256) void k_prep(const float* __restrict__ W,
                                              unsigned short* __restrict__ Bf)
{
  int id = blockIdx.x * 256 + threadIdx.x;      // 0..4095
  if (id >= 16 * 4 * 64) return;
  int l = id & 63, ks = (id >> 6) & 3, nfg = id >> 8;
  int col = nfg * 16 + (l & 15);
  int k0  = ks * 32 + (l >> 4) * 8;
  unsigned short v[8];
  #pragma unroll
  for (int j = 0; j < 8; ++j) v[j] = f2bf(W[(k0 + j) * HIDDEN + col]);
  *(uint4*)(Bf + (size_t)id * 8) = *(const uint4*)v;
}

// ---------------- MFMA GEMM (+ edge histogram fused as trailing blocks) ----------------
// blocks [0, gemmBlocks): 32 nodes each, 4 waves, wave w == head w
// blocks [gemmBlocks, gemmBlocks+HISTB): edge-degree histogram (independent work)
__global__ __launch_bounds__(256) void k_gemmhist(
    const float* __restrict__ x, const unsigned short* __restrict__ Bf,
    const float* __restrict__ att_s, const float* __restrict__ att_d,
    unsigned short* __restrict__ h16, float* __restrict__ a_src, float* __restrict__ a_dst,
    const int* __restrict__ ei, int* __restrict__ count,
    int nNodes, int E, int gemmBlocks)
{
  __shared__ unsigned short As[32 * FIN];       // 8 KB, XOR-swizzled
  const int t = threadIdx.x;

  if (blockIdx.x >= gemmBlocks) {               // ---- histogram part ----
    int i = (blockIdx.x - gemmBlocks) * 256 + t;
    int stride = HISTB * 256;
    for (int e = i; e < E; e += stride) atomicAdd(&count[ei[E + e]], 1);
    return;                                     // self loops handled in scan1 (+1)
  }

  const int n0 = blockIdx.x * 32;

  // ---- stage x tile (fp32 -> bf16) into LDS with (row&7)<<4 byte-XOR swizzle ----
  {
    const int row = t >> 3;                     // 0..31
    const int g   = n0 + row;
    const int c0  = (t & 7) * 16;               // float offset in row
    float4 f0, f1, f2, f3;
    if (g < nNodes) {
      const float* xr = x + (size_t)g * FIN + c0;
      f0 = *(const float4*)(xr + 0);  f1 = *(const float4*)(xr + 4);
      f2 = *(const float4*)(xr + 8);  f3 = *(const float4*)(xr + 12);
    } else {
      f0 = f1 = f2 = f3 = make_float4(0.f, 0.f, 0.f, 0.f);
    }
    unsigned short u[16];
    u[0]=f2bf(f0.x); u[1]=f2bf(f0.y); u[2]=f2bf(f0.z); u[3]=f2bf(f0.w);
    u[4]=f2bf(f1.x); u[5]=f2bf(f1.y); u[6]=f2bf(f1.z); u[7]=f2bf(f1.w);
    u[8]=f2bf(f2.x); u[9]=f2bf(f2.y); u[10]=f2bf(f2.z); u[11]=f2bf(f2.w);
    u[12]=f2bf(f3.x); u[13]=f2bf(f3.y); u[14]=f2bf(f3.z); u[15]=f2bf(f3.w);
    const int sw = (row & 7) << 4;
    char* base = (char*)As + row * 256;
    *(uint4*)(base + (((t & 7) * 32)      ^ sw)) = *(const uint4*)(u + 0);
    *(uint4*)(base + (((t & 7) * 32 + 16) ^ sw)) = *(const uint4*)(u + 8);
  }
  __syncthreads();

  const int w    = t >> 6;                      // wave == head
  const int l    = t & 63;
  const int lrow = l & 15;

  frag_ab bfr[4][4];                            // [nf][ks]
  #pragma unroll
  for (int nf = 0; nf < 4; ++nf)
    #pragma unroll
    for (int ks = 0; ks < 4; ++ks)
      bfr[nf][ks] = *(const frag_ab*)(Bf + (size_t)(((w * 4 + nf) * 4 + ks) * 64 + l) * 8);

  frag_ab afr[2][4];                            // [mf][ks]
  const int lsw = (lrow & 7) << 4;
  #pragma unroll
  for (int mf = 0; mf < 2; ++mf)
    #pragma unroll
    for (int ks = 0; ks < 4; ++ks) {
      int byte = (mf * 16 + lrow) * 256 + ((ks * 64 + (l >> 4) * 16) ^ lsw);
      afr[mf][ks] = *(const frag_ab*)((const char*)As + byte);
    }

  frag_cd acc[2][4];
  #pragma unroll
  for (int mf = 0; mf < 2; ++mf)
    #pragma unroll
    for (int nf = 0; nf < 4; ++nf)
      acc[mf][nf] = (frag_cd){0.f, 0.f, 0.f, 0.f};
  #pragma unroll
  for (int ks = 0; ks < 4; ++ks)
    #pragma unroll
    for (int mf = 0; mf < 2; ++mf)
      #pragma unroll
      for (int nf = 0; nf < 4; ++nf)
        acc[mf][nf] = __builtin_amdgcn_mfma_f32_16x16x32_bf16(
            afr[mf][ks], bfr[nf][ks], acc[mf][nf], 0, 0, 0);

  float asw[4], adw[4];
  #pragma unroll
  for (int nf = 0; nf < 4; ++nf) {
    asw[nf] = att_s[w * 64 + nf * 16 + lrow];
    adw[nf] = att_d[w * 64 + nf * 16 + lrow];
  }

  #pragma unroll
  for (int mf = 0; mf < 2; ++mf) {
    #pragma unroll
    for (int r = 0; r < 4; ++r) {
      const int rowg = n0 + mf * 16 + (l >> 4) * 4 + r;
      if (rowg < nNodes) {
        #pragma unroll
        for (int nf = 0; nf < 4; ++nf)
          h16[(size_t)rowg * HIDDEN + w * 64 + nf * 16 + lrow] = f2bf(acc[mf][nf][r]);
      }
      float ss = 0.f, sd = 0.f;
      #pragma unroll
      for (int nf = 0; nf < 4; ++nf) {
        ss = fmaf(acc[mf][nf][r], asw[nf], ss);
        sd = fmaf(acc[mf][nf][r], adw[nf], sd);
      }
      #pragma unroll
      for (int off2 = 1; off2 <= 8; off2 <<= 1) {
        ss += __shfl_xor(ss, off2, 64);
        sd += __shfl_xor(sd, off2, 64);
      }
      if (lrow == 0 && rowg < nNodes) {
        a_src[rowg * HEADS + w] = ss;
        a_dst[rowg * HEADS + w] = sd;
      }
    }
  }
}

// ---------------- scan1: block-local exclusive scan of (cnt[i]+1) ----------------
__global__ __launch_bounds__(256) void k_scan1(const int* __restrict__ cnt,
                                               int* __restrict__ offs,
                                               int* __restrict__ bsum, int n)
{
  int t = threadIdx.x, b = blockIdx.x;
  int i = b * 256 + t;
  int v = (i < n) ? cnt[i] + 1 : 0;   // +1 = self loop (no atomics needed)
  int sc = v;
  #pragma unroll
  for (int d2 = 1; d2 < 64; d2 <<= 1) {
    int u = __shfl_up(sc, d2, 64);
    if ((t & 63) >= d2) sc += u;
  }
  __shared__ int wsum[4];
  if ((t & 63) == 63) wsum[t >> 6] = sc;
  __syncthreads();
  int base = 0;
  for (int w = 0; w < (t >> 6); ++w) base += wsum[w];
  int incl = sc + base;
  if (i < n) offs[i] = incl - v;          // exclusive within block
  if (t == 255) bsum[b] = incl;           // block total
}

// ---------------- scan23 fused: add exclusive block offset; init cursor ----------------
__global__ __launch_bounds__(256) void k_scan23(int* __restrict__ offs,
                                                const int* __restrict__ bsum,
                                                int* __restrict__ cursor,
                                                int n, int nb, int total)
{
  int t = threadIdx.x, b = blockIdx.x;
  // blockBase = sum of bsum[j] for j < b (nb <= ~1024; thread-parallel + reduce)
  float dummy; (void)dummy;
  int partial = 0;
  for (int j = t; j < b; j += 256) partial += bsum[j];
  #pragma unroll
  for (int off2 = 32; off2; off2 >>= 1) partial += __shfl_xor(partial, off2, 64);
  __shared__ int ws4[4];
  if ((t & 63) == 0) ws4[t >> 6] = partial;
  __syncthreads();
  int blockBase = ws4[0] + ws4[1] + ws4[2] + ws4[3];

  int i = b * 256 + t;
  if (i < n) {
    int o = offs[i] + blockBase;
    offs[i] = o;
    cursor[i] = o;
  }
  if (i == 0) offs[n] = total;
}

// ---------------- CSR scatter: src indices into dst-sorted slots ----------------
__global__ __launch_bounds__(256) void k_scatter(
    const int* __restrict__ ei, int* __restrict__ cursor,
    int* __restrict__ ssrc, int E, int N)
{
  int e = blockIdx.x * 256 + threadIdx.x;
  int tot = E + N;
  if (e >= tot) return;
  int s, d;
  if (e < E) { s = ei[e]; d = ei[E + e]; }
  else       { s = e - E; d = s; }        // self loop
  int pos = atomicAdd(&cursor[d], 1);
  ssrc[pos] = s;
}

// ---------------- aggregation: one WAVE per node; fused softmax+bias+ELU ----------------
__global__ __launch_bounds__(256) void k_agg(
    const unsigned short* __restrict__ h16, const int* __restrict__ offs,
    const int* __restrict__ ssrc,
    const float* __restrict__ a_src, const float* __restrict__ a_dst,
    const float* __restrict__ bias,
    unsigned short* __restrict__ outn, int N)
{
  const int wid0 = blockIdx.x * WPB + (threadIdx.x >> 6);
  if (wid0 >= N) return;
  const int wid  = __builtin_amdgcn_readfirstlane(wid0);   // wave-uniform -> s_loads
  const int lane = threadIdx.x & 63;
  const int head = lane >> 4;
  const int col  = lane << 2;

  const int beg = offs[wid], end = offs[wid + 1];
  const float ad = a_dst[wid * 4 + head];

  float4 acc = make_float4(0.f, 0.f, 0.f, 0.f);
  float den = 0.f;
  int k = beg;

  for (; k + 8 <= end; k += 8) {
    int s0 = ssrc[k + 0], s1 = ssrc[k + 1], s2 = ssrc[k + 2], s3 = ssrc[k + 3];
    int s4 = ssrc[k + 4], s5 = ssrc[k + 5], s6 = ssrc[k + 6], s7 = ssrc[k + 7];
    float e0 = a_src[s0 * 4 + head], e1 = a_src[s1 * 4 + head];
    float e2 = a_src[s2 * 4 + head], e3 = a_src[s3 * 4 + head];
    float e4 = a_src[s4 * 4 + head], e5 = a_src[s5 * 4 + head];
    float e6 = a_src[s6 * 4 + head], e7 = a_src[s7 * 4 + head];
    ushort4 h0 = *(const ushort4*)(h16 + (size_t)s0 * HIDDEN + col);
    ushort4 h1 = *(const ushort4*)(h16 + (size_t)s1 * HIDDEN + col);
    ushort4 h2 = *(const ushort4*)(h16 + (size_t)s2 * HIDDEN + col);
    ushort4 h3 = *(const ushort4*)(h16 + (size_t)s3 * HIDDEN + col);
    ushort4 h4 = *(const ushort4*)(h16 + (size_t)s4 * HIDDEN + col);
    ushort4 h5 = *(const ushort4*)(h16 + (size_t)s5 * HIDDEN + col);
    ushort4 h6 = *(const ushort4*)(h16 + (size_t)s6 * HIDDEN + col);
    ushort4 h7 = *(const ushort4*)(h16 + (size_t)s7 * HIDDEN + col);
    float w0, w1, w2, w3, w4, w5, w6, w7;
    e0 += ad; e0 = e0 > 0.f ? e0 : 0.2f * e0; w0 = __expf(e0);
    e1 += ad; e1 = e1 > 0.f ? e1 : 0.2f * e1; w1 = __expf(e1);
    e2 += ad; e2 = e2 > 0.f ? e2 : 0.2f * e2; w2 = __expf(e2);
    e3 += ad; e3 = e3 > 0.f ? e3 : 0.2f * e3; w3 = __expf(e3);
    e4 += ad; e4 = e4 > 0.f ? e4 : 0.2f * e4; w4 = __expf(e4);
    e5 += ad; e5 = e5 > 0.f ? e5 : 0.2f * e5; w5 = __expf(e5);
    e6 += ad; e6 = e6 > 0.f ? e6 : 0.2f * e6; w6 = __expf(e6);
    e7 += ad; e7 = e7 > 0.f ? e7 : 0.2f * e7; w7 = __expf(e7);
    den += ((w0 + w1) + (w2 + w3)) + ((w4 + w5) + (w6 + w7));
    acc.x = fmaf(bf2f(h0.x), w0, acc.x); acc.y = fmaf(bf2f(h0.y), w0, acc.y);
    acc.z = fmaf(bf2f(h0.z), w0, acc.z); acc.w = fmaf(bf2f(h0.w), w0, acc.w);
    acc.x = fmaf(bf2f(h1.x), w1, acc.x); acc.y = fmaf(bf2f(h1.y), w1, acc.y);
    acc.z = fmaf(bf2f(h1.z), w1, acc.z); acc.w = fmaf(bf2f(h1.w), w1, acc.w);
    acc.x = fmaf(bf2f(h2.x), w2, acc.x); acc.y = fmaf(bf2f(h2.y), w2, acc.y);
    acc.z = fmaf(bf2f(h2.z), w2, acc.z); acc.w = fmaf(bf2f(h2.w), w2, acc.w);
    acc.x = fmaf(bf2f(h3.x), w3, acc.x); acc.y = fmaf(bf2f(h3.y), w3, acc.y);
    acc.z = fmaf(bf2f(h3.z), w3, acc.z); acc.w = fmaf(bf2f(h3.w), w3, acc.w);
    acc.x = fmaf(bf2f(h4.x), w4, acc.x); acc.y = fmaf(bf2f(h4.y), w4, acc.y);
    acc.z = fmaf(bf2f(h4.z), w4, acc.z); acc.w = fmaf(bf2f(h4.w), w4, acc.w);
    acc.x = fmaf(bf2f(h5.x), w5, acc.x); acc.y = fmaf(bf2f(h5.y), w5, acc.y);
    acc.z = fmaf(bf2f(h5.z), w5, acc.z); acc.w = fmaf(bf2f(h5.w), w5, acc.w);
    acc.x = fmaf(bf2f(h6.x), w6, acc.x); acc.y = fmaf(bf2f(h6.y), w6, acc.y);
    acc.z = fmaf(bf2f(h6.z), w6, acc.z); acc.w = fmaf(bf2f(h6.w), w6, acc.w);
    acc.x = fmaf(bf2f(h7.x), w7, acc.x); acc.y = fmaf(bf2f(h7.y), w7, acc.y);
    acc.z = fmaf(bf2f(h7.z), w7, acc.z); acc.w = fmaf(bf2f(h7.w), w7, acc.w);
  }
  for (; k < end; ++k) {
    int s = ssrc[k];
    float e = a_src[s * 4 + head] + ad;
    e = e > 0.f ? e : 0.2f * e;
    float w = __expf(e);
    ushort4 hv = *(const ushort4*)(h16 + (size_t)s * HIDDEN + col);
    den += w;
    acc.x = fmaf(bf2f(hv.x), w, acc.x); acc.y = fmaf(bf2f(hv.y), w, acc.y);
    acc.z = fmaf(bf2f(hv.z), w, acc.z); acc.w = fmaf(bf2f(hv.w), w, acc.w);
  }

  const float inv = 1.f / den;          // den > 0 guaranteed by self loop
  float4 bv = *(const float4*)&bias[col];
  float4 o;
  o.x = fmaf(acc.x, inv, bv.x); o.x = o.x > 0.f ? o.x : expm1f(o.x);
  o.y = fmaf(acc.y, inv, bv.y); o.y = o.y > 0.f ? o.y : expm1f(o.y);
  o.z = fmaf(acc.z, inv, bv.z); o.z = o.z > 0.f ? o.z : expm1f(o.z);
  o.w = fmaf(acc.w, inv, bv.w); o.w = o.w > 0.f ? o.w : expm1f(o.w);

  ushort4 ov;
  ov.x = f2bf(o.x); ov.y = f2bf(o.y); ov.z = f2bf(o.z); ov.w = f2bf(o.w);
  *(ushort4*)(outn + (size_t)wid * HIDDEN + col) = ov;
}

// ---------------- parallel pooling: run-length partial sums, atomic flush ----------------
__global__ __launch_bounds__(256) void k_poolp(
    const unsigned short* __restrict__ outn, const int* __restrict__ batch,
    float* __restrict__ pooled, float* __restrict__ cntg, int N)
{
  const int t = threadIdx.x;
  const int n0 = blockIdx.x * PCHUNK;
  if (n0 >= N) return;
  const int n1 = (n0 + PCHUNK < N) ? n0 + PCHUNK : N;

  int cur = batch[n0];
  float run = 0.f;
  int runlen = 0;
  int n = n0;
  for (; n + 4 <= n1; n += 4) {
    // 4 independent row loads in flight
    unsigned short r0 = outn[(size_t)(n + 0) * HIDDEN + t];
    unsigned short r1 = outn[(size_t)(n + 1) * HIDDEN + t];
    unsigned short r2 = outn[(size_t)(n + 2) * HIDDEN + t];
    unsigned short r3 = outn[(size_t)(n + 3) * HIDDEN + t];
    int g0 = batch[n + 0], g3 = batch[n + 3];
    if (g0 == cur && g3 == cur) {
      run += (bf2f(r0) + bf2f(r1)) + (bf2f(r2) + bf2f(r3));
      runlen += 4;
    } else {
      unsigned short rr[4] = {r0, r1, r2, r3};
      #pragma unroll
      for (int j = 0; j < 4; ++j) {
        int g = batch[n + j];
        if (g != cur) {
          atomicAdd(&pooled[cur * HIDDEN + t], run);
          if (t == 0) atomicAdd(&cntg[cur], (float)runlen);
          run = 0.f; runlen = 0; cur = g;
        }
        run += bf2f(rr[j]); runlen++;
      }
    }
  }
  for (; n < n1; ++n) {
    int g = batch[n];
    if (g != cur) {
      atomicAdd(&pooled[cur * HIDDEN + t], run);
      if (t == 0) atomicAdd(&cntg[cur], (float)runlen);
      run = 0.f; runlen = 0; cur = g;
    }
    run += bf2f(outn[(size_t)n * HIDDEN + t]); runlen++;
  }
  atomicAdd(&pooled[cur * HIDDEN + t], run);
  if (t == 0) atomicAdd(&cntg[cur], (float)runlen);
}

// ---------------- final: mean + FC from pooled sums ----------------
__global__ __launch_bounds__(64) void k_fc(
    const float* __restrict__ pooled, const float* __restrict__ cntg,
    const float* __restrict__ fc_w, const float* __restrict__ fc_b, float* __restrict__ out)
{
  int g = blockIdx.x, l = threadIdx.x;
  float acc = 0.f;
  #pragma unroll
  for (int j = 0; j < HIDDEN / 64; ++j) acc += pooled[g * HIDDEN + j * 64 + l] * fc_w[j * 64 + l];
  #pragma unroll
  for (int off2 = 32; off2; off2 >>= 1) acc += __shfl_xor(acc, off2, 64);
  if (l == 0) out[g] = acc / fmaxf(cntg[g], 1.0f) + fc_b[0];
}

extern "C" void kernel_launch(void* const* d_in, const int* in_sizes, int n_in,
                              void* d_out, int out_size, void* d_ws, size_t ws_size,
                              hipStream_t stream)
{
  const float* x     = (const float*)d_in[0];
  const int*   ei    = (const int*)  d_in[1];   // [2,E] flat: [0..E)=src, [E..2E)=dst
  /* d_in[2] edge_attr: unused by reference */
  const int*   batch = (const int*)  d_in[3];
  const float* W     = (const float*)d_in[4];
  const float* att_s = (const float*)d_in[5];
  const float* att_d = (const float*)d_in[6];
  const float* bias  = (const float*)d_in[7];
  const float* fc_w  = (const float*)d_in[8];
  const float* fc_b  = (const float*)d_in[9];
  float* out = (float*)d_out;

  const int N   = in_sizes[0] / FIN;
  const int E   = in_sizes[1] / 2;
  const int TOT = E + N;

  char* p = (char*)d_ws;
  size_t o = 0;
  auto alloc = [&](size_t bytes) -> void* {
    void* r = p + o;
    o = (o + bytes + 255) & ~(size_t)255;
    return r;
  };
  // zero-init region first: one memset covers [count | pooled | cntg]
  int*   count  = (int*)  alloc((size_t)N * sizeof(int));
  float* pooled = (float*)alloc((size_t)NGRAPH * HIDDEN * sizeof(float));
  float* cntg   = (float*)alloc((size_t)NGRAPH * sizeof(float));
  size_t zeroBytes = o;
  unsigned short* h16 = (unsigned short*)alloc((size_t)N * HIDDEN * sizeof(unsigned short));
  unsigned short* Bf  = (unsigned short*)alloc((size_t)FIN * HIDDEN * sizeof(unsigned short));
  float* a_src  = (float*)alloc((size_t)N * 4 * sizeof(float));
  float* a_dst  = (float*)alloc((size_t)N * 4 * sizeof(float));
  int*   offs   = (int*)  alloc((size_t)(N + 1) * sizeof(int));
  int*   cursor = (int*)  alloc((size_t)N * sizeof(int));
  int*   bsum   = (int*)  alloc(4096);
  int*   ssrc   = (int*)  alloc((size_t)TOT * sizeof(int));
  unsigned short* outn = (unsigned short*)alloc((size_t)N * HIDDEN * sizeof(unsigned short));
  (void)n_in; (void)out_size; (void)ws_size;

  (void)hipMemsetAsync(d_ws, 0, zeroBytes, stream);

  const int gemmBlocks = (N + 31) / 32;
  hipLaunchKernelGGL(k_prep, dim3(16), dim3(256), 0, stream, W, Bf);
  hipLaunchKernelGGL(k_gemmhist, dim3(gemmBlocks + HISTB), dim3(256), 0, stream,
                     x, Bf, att_s, att_d, h16, a_src, a_dst, ei, count, N, E, gemmBlocks);
  const int sb = (N + 255) / 256;
  hipLaunchKernelGGL(k_scan1, dim3(sb), dim3(256), 0, stream, count, offs, bsum, N);
  hipLaunchKernelGGL(k_scan23, dim3(sb), dim3(256), 0, stream, offs, bsum, cursor, N, sb, TOT);
  hipLaunchKernelGGL(k_scatter, dim3((TOT + 255) / 256), dim3(256), 0, stream,
                     ei, cursor, ssrc, E, N);
  hipLaunchKernelGGL(k_agg, dim3((N + WPB - 1) / WPB), dim3(256), 0, stream,
                     h16, offs, ssrc, a_src, a_dst, bias, outn, N);
  hipLaunchKernelGGL(k_poolp, dim3((N + PCHUNK - 1) / PCHUNK), dim3(256), 0, stream,
                     outn, batch, pooled, cntg, N);
  hipLaunchKernelGGL(k_fc, dim3(NGRAPH), dim3(64), 0, stream,
                     pooled, cntg, fc_w, fc_b, out);
}